// Round 10
// baseline (159.326 us; speedup 1.0000x reference)
//
#include <hip/hip_runtime.h>

#define NB 8
#define NS 2048
#define ND 64
#define LOG2E 1.44269504f

typedef _Float16 half8 __attribute__((ext_vector_type(8)));
typedef __attribute__((ext_vector_type(4))) float floatx4;

__device__ __forceinline__ half8 cvt8(const float* p) {
    float4 a = *(const float4*)p;
    float4 b = *(const float4*)(p + 4);
    half8 h = {(_Float16)a.x, (_Float16)a.y, (_Float16)a.z, (_Float16)a.w,
               (_Float16)b.x, (_Float16)b.y, (_Float16)b.z, (_Float16)b.w};
    return h;
}
// column read of row-major W[64][64]: 8 fp32 at stride 64, cast fp16
__device__ __forceinline__ half8 cvtWcol(const float* base) {
    half8 h;
#pragma unroll
    for (int j = 0; j < 8; ++j) h[j] = (_Float16)base[j * 64];
    return h;
}
__device__ __forceinline__ unsigned f2bf(float f) {   // RNE to bf16 (low 16 of result)
    unsigned u = __builtin_bit_cast(unsigned, f);
    return (u + 0x7fffu + ((u >> 16) & 1u)) >> 16;
}
__device__ __forceinline__ float bf2f(unsigned lo16) {
    return __builtin_bit_cast(float, lo16 << 16);
}

// ---------------- QKV projection, 256 blocks x 512 thr (1 block/CU) ----------
// Block = 64 rows x all 192 cols. Wave w: q-rows (w&3)*16, col-tiles (w>>2)*6..+5.
// Q pre-scaled by log2(e) so attn uses v_exp_f32 (2^x) directly.
__global__ __launch_bounds__(512, 2) void qkv_proj(
    const float* __restrict__ x,
    const float* __restrict__ Wq, const float* __restrict__ bq,
    const float* __restrict__ Wk, const float* __restrict__ bk,
    const float* __restrict__ Wv, const float* __restrict__ bv,
    _Float16* __restrict__ Qg, _Float16* __restrict__ Kg,
    _Float16* __restrict__ Vt)
{
    __shared__ _Float16 vt[64 * 72];   // V tile transposed [col][row], pad 72

    const int tid  = threadIdx.x;
    const int wv   = tid >> 6;
    const int l    = tid & 63;
    const int quad = l >> 4;
    const int tx   = l & 15;

    const int b  = blockIdx.x & 7;            // XCD-pinned batch
    const int n0 = (blockIdx.x >> 3) * 64;
    const int rq = (wv & 3) * 16;             // wave's 16-row group
    const int g  = wv >> 2;                   // col-tile group (0: tiles 0-5, 1: 6-11)

    const float* xr = x + ((size_t)b * NS + n0 + rq + tx) * ND + quad * 8;
    half8 a0 = cvt8(xr);
    half8 a1 = cvt8(xr + 32);

    const floatx4 zf = {0.f, 0.f, 0.f, 0.f};

#pragma unroll
    for (int i = 0; i < 6; ++i) {
        const int ct = g * 6 + i;             // 0..11, wave-uniform
        const int m  = ct >> 2;
        const int lcol = (ct & 3) * 16 + tx;

        const float* Wm;
        const float* Bm;
        if (m == 0)      { Wm = Wq; Bm = bq; }
        else if (m == 1) { Wm = Wk; Bm = bk; }
        else             { Wm = Wv; Bm = bv; }

        half8 b0 = cvtWcol(Wm + (quad * 8) * 64 + lcol);
        half8 b1 = cvtWcol(Wm + (32 + quad * 8) * 64 + lcol);

        floatx4 acc = __builtin_amdgcn_mfma_f32_16x16x32_f16(a0, b0, zf, 0, 0, 0);
        acc = __builtin_amdgcn_mfma_f32_16x16x32_f16(a1, b1, acc, 0, 0, 0);
        const float bias = Bm[lcol];

        if (m == 0) {
#pragma unroll
            for (int r = 0; r < 4; ++r)
                Qg[((size_t)b * NS + n0 + rq + quad * 4 + r) * ND + lcol] =
                    (_Float16)((acc[r] + bias) * LOG2E);
        } else if (m == 1) {
#pragma unroll
            for (int r = 0; r < 4; ++r)
                Kg[((size_t)b * NS + n0 + rq + quad * 4 + r) * ND + lcol] = (_Float16)(acc[r] + bias);
        } else {
#pragma unroll
            for (int r = 0; r < 4; ++r)
                vt[lcol * 72 + rq + quad * 4 + r] = (_Float16)(acc[r] + bias);
        }
    }
    __syncthreads();
    {   // Vt[b][d][n0..n0+63]: 512 thr, 8 per dim, 8 halfs (16B) each
        const int d = tid >> 3, seg = tid & 7;
        uint4 p = *(uint4*)&vt[d * 72 + seg * 8];
        *(uint4*)(Vt + ((size_t)b * ND + d) * NS + n0 + seg * 8) = p;
    }
}

// ---------------- fused masked attention: 256 blocks (1/CU), e in bf16 regs ----
// Block = (batch b, 64 q-rows). 8 waves = 4 q-subtiles x 2 key-halves (1024 keys).
// Pass 1: e = 2^(s') for 16x1024 per wave, packed bf16 2-per-VGPR (128 regs),
// l = sum e. Mask: e > l/N <=> p > mean(p) = 1/N. Pass 2: unpack, mask,
// per-wave LDS transpose, PV. No max: |s| <~ 45 << 127 (2^x range).
__global__ __launch_bounds__(512, 2) void attn(
    const _Float16* __restrict__ Qg,
    const _Float16* __restrict__ Kg,
    const _Float16* __restrict__ Vt,
    float* __restrict__ out)
{
    // pbuf: 8 waves x 16 rows x 56 stride fp16 = 14336 B; obuf union: 128x68 fp32 = 34816 B
    __shared__ __align__(16) unsigned char smraw[128 * 68 * 4];
    __shared__ float lsh[128];
    _Float16* pbuf = (_Float16*)smraw;
    float*    obuf = (float*)smraw;

    const int tid  = threadIdx.x;
    const int wv   = tid >> 6;
    const int l    = tid & 63;
    const int quad = l >> 4;
    const int tx   = l & 15;
    const int qs   = wv & 3;        // q-subtile
    const int kh   = wv >> 2;       // key half

    const int b  = blockIdx.x & 7;
    const int q0 = (blockIdx.x >> 3) * 64;

    const _Float16* Qb = Qg + ((size_t)b * NS + q0 + qs * 16) * ND;
    const _Float16* Kb = Kg + ((size_t)b * NS + kh * 1024) * ND;
    const _Float16* Vb = Vt + (size_t)b * ND * NS + kh * 1024;

    half8 qf0 = *(const half8*)(Qb + (size_t)tx * ND + quad * 8);
    half8 qf1 = *(const half8*)(Qb + (size_t)tx * ND + 32 + quad * 8);

    const floatx4 zf = {0.f, 0.f, 0.f, 0.f};

    // ---- pass 1: 64 independent 16-key subtiles; e packed bf16 into 128 VGPRs ----
    unsigned e2[128];
    float lacc[4] = {0.f, 0.f, 0.f, 0.f};
#pragma unroll
    for (int s = 0; s < 64; ++s) {
        const _Float16* Kr = Kb + (size_t)(s * 16 + tx) * ND + quad * 8;
        half8 k0 = *(const half8*)Kr;
        half8 k1 = *(const half8*)(Kr + 32);
        floatx4 c = __builtin_amdgcn_mfma_f32_16x16x32_f16(qf0, k0, zf, 0, 0, 0);
        c = __builtin_amdgcn_mfma_f32_16x16x32_f16(qf1, k1, c, 0, 0, 0);
        float e0 = __builtin_amdgcn_exp2f(c[0]);
        float e1 = __builtin_amdgcn_exp2f(c[1]);
        float ee2 = __builtin_amdgcn_exp2f(c[2]);
        float e3 = __builtin_amdgcn_exp2f(c[3]);
        lacc[0] += e0; lacc[1] += e1; lacc[2] += ee2; lacc[3] += e3;
        e2[2 * s]     = f2bf(e0)  | (f2bf(e1) << 16);
        e2[2 * s + 1] = f2bf(ee2) | (f2bf(e3) << 16);
    }
    // reduce over the 16 tx lanes, publish per wave, merge the 2 halves
#pragma unroll
    for (int off = 1; off < 16; off <<= 1)
#pragma unroll
        for (int r = 0; r < 4; ++r)
            lacc[r] += __shfl_xor(lacc[r], off);
    if (tx == 0) {
#pragma unroll
        for (int r = 0; r < 4; ++r)
            lsh[wv * 16 + quad * 4 + r] = lacc[r];
    }
    __syncthreads();

    float inv[4], thr[4];
#pragma unroll
    for (int r = 0; r < 4; ++r) {
        const int row = quad * 4 + r;
        float L = lsh[qs * 16 + row] + lsh[(qs + 4) * 16 + row];
        inv[r] = 1.f / L;
        thr[r] = L * (1.f / (float)NS);
    }

    // ---- pass 2: 32 chunks of 32 keys: unpack e, mask, LDS transpose, PV ----
    floatx4 o[4] = {zf, zf, zf, zf};
    _Float16* pb = pbuf + wv * (16 * 56);

#pragma unroll
    for (int c = 0; c < 32; ++c) {
        half8 vf[4];
#pragma unroll
        for (int nt = 0; nt < 4; ++nt)   // V early: consumed after LDS round-trip
            vf[nt] = *(const half8*)(Vb + (size_t)(nt * 16 + tx) * NS + c * 32 + quad * 8);

#pragma unroll
        for (int h = 0; h < 2; ++h) {
            const int s = 2 * c + h;
            unsigned u0 = e2[2 * s], u1 = e2[2 * s + 1];
            float ev[4] = {bf2f(u0 & 0xffffu), bf2f(u0 >> 16),
                           bf2f(u1 & 0xffffu), bf2f(u1 >> 16)};
#pragma unroll
            for (int r = 0; r < 4; ++r) {
                float w = (ev[r] > thr[r]) ? ev[r] * inv[r] : 0.f;
                pb[(quad * 4 + r) * 56 + h * 16 + tx] = (_Float16)w;
            }
        }
        // per-wave DS FIFO: this read sees this wave's writes above
        half8 af = *(const half8*)(pb + tx * 56 + quad * 8);
#pragma unroll
        for (int nt = 0; nt < 4; ++nt)
            o[nt] = __builtin_amdgcn_mfma_f32_16x16x32_f16(af, vf[nt], o[nt], 0, 0, 0);
    }

    __syncthreads();   // all pbuf reads complete before obuf reuse
#pragma unroll
    for (int nt = 0; nt < 4; ++nt)
#pragma unroll
        for (int r = 0; r < 4; ++r)
            obuf[(wv * 16 + quad * 4 + r) * 68 + nt * 16 + tx] = o[nt][r];
    __syncthreads();

    {   // merge the 2 key-halves, store: thread -> (row 0..63, 8 cols)
        const int row = tid >> 3;            // 0..63
        const int c8  = (tid & 7) * 8;
        const int sq  = row >> 4;            // q-subtile of this row
        const int rl  = row & 15;
        float4 s0 = {0.f, 0.f, 0.f, 0.f}, s1 = s0;
#pragma unroll
        for (int h = 0; h < 2; ++h) {
            const float* src = &obuf[((sq + 4 * h) * 16 + rl) * 68 + c8];
            float4 a = *(const float4*)src;
            float4 bb = *(const float4*)(src + 4);
            s0.x += a.x; s0.y += a.y; s0.z += a.z; s0.w += a.w;
            s1.x += bb.x; s1.y += bb.y; s1.z += bb.z; s1.w += bb.w;
        }
        float* dst = out + ((size_t)b * NS + q0 + row) * ND + c8;
        *(float4*)dst = s0;
        *(float4*)(dst + 4) = s1;
    }
}

extern "C" void kernel_launch(void* const* d_in, const int* in_sizes, int n_in,
                              void* d_out, int out_size, void* d_ws, size_t ws_size,
                              hipStream_t stream) {
    const float* x  = (const float*)d_in[0];
    const float* Wq = (const float*)d_in[1];
    const float* bq = (const float*)d_in[2];
    const float* Wk = (const float*)d_in[3];
    const float* bk = (const float*)d_in[4];
    const float* Wv = (const float*)d_in[5];
    const float* bv = (const float*)d_in[6];

    _Float16* Qg = (_Float16*)d_ws;
    _Float16* Kg = Qg + (size_t)NB * NS * ND;
    _Float16* Vt = Kg + (size_t)NB * NS * ND;

    qkv_proj<<<NB * (NS / 64), 512, 0, stream>>>(x, Wq, bq, Wk, bk, Wv, bv, Qg, Kg, Vt);
    attn<<<NB * (NS / 64), 512, 0, stream>>>(Qg, Kg, Vt, (float*)d_out);
}

// Round 11
// 133.789 us; speedup vs baseline: 1.1909x; 1.1909x over previous
//
#include <hip/hip_runtime.h>

#define NB 8
#define NS 2048
#define ND 64
#define LOG2E 1.44269504f

typedef _Float16 half8 __attribute__((ext_vector_type(8)));
typedef _Float16 half2v __attribute__((ext_vector_type(2)));
typedef __attribute__((ext_vector_type(4))) float floatx4;

__device__ __forceinline__ half8 cvt8(const float* p) {
    float4 a = *(const float4*)p;
    float4 b = *(const float4*)(p + 4);
    half8 h = {(_Float16)a.x, (_Float16)a.y, (_Float16)a.z, (_Float16)a.w,
               (_Float16)b.x, (_Float16)b.y, (_Float16)b.z, (_Float16)b.w};
    return h;
}
// column read of row-major W[64][64]: 8 fp32 at stride 64, cast fp16
__device__ __forceinline__ half8 cvtWcol(const float* base) {
    half8 h;
#pragma unroll
    for (int j = 0; j < 8; ++j) h[j] = (_Float16)base[j * 64];
    return h;
}
__device__ __forceinline__ unsigned f2bf(float f) {   // RNE to bf16 (low 16 of result)
    unsigned u = __builtin_bit_cast(unsigned, f);
    return (u + 0x7fffu + ((u >> 16) & 1u)) >> 16;
}
__device__ __forceinline__ float bf2f(unsigned lo16) {
    return __builtin_bit_cast(float, lo16 << 16);
}

// ---------------- QKV projection via fp16 MFMA (r9 verbatim; XCD-aligned) -----
__global__ __launch_bounds__(256) void qkv_proj(
    const float* __restrict__ x,
    const float* __restrict__ Wq, const float* __restrict__ bq,
    const float* __restrict__ Wk, const float* __restrict__ bk,
    const float* __restrict__ Wv, const float* __restrict__ bv,
    _Float16* __restrict__ Qg, _Float16* __restrict__ Kg,
    _Float16* __restrict__ Vt)
{
    __shared__ _Float16 vt[64 * 18];

    const int tid  = threadIdx.x;
    const int wv   = tid >> 6;
    const int l    = tid & 63;
    const int quad = l >> 4;
    const int tx   = l & 15;

    const int b  = blockIdx.x & 7;            // XCD-pinned batch (matches attn)
    const int n0 = (blockIdx.x >> 3) * 16;

    const float* xr = x + ((size_t)b * NS + n0 + tx) * ND + quad * 8;
    half8 a0 = cvt8(xr);
    half8 a1 = cvt8(xr + 32);

    const floatx4 zf = {0.f, 0.f, 0.f, 0.f};

#pragma unroll
    for (int i = 0; i < 3; ++i) {
        const int ct = wv * 3 + i;            // 0..11, wave-uniform
        const int m  = ct >> 2;
        const int lcol = (ct & 3) * 16 + tx;

        const float* Wm;
        const float* Bm;
        if (m == 0)      { Wm = Wq; Bm = bq; }
        else if (m == 1) { Wm = Wk; Bm = bk; }
        else             { Wm = Wv; Bm = bv; }

        half8 b0 = cvtWcol(Wm + (quad * 8) * 64 + lcol);
        half8 b1 = cvtWcol(Wm + (32 + quad * 8) * 64 + lcol);

        floatx4 acc = __builtin_amdgcn_mfma_f32_16x16x32_f16(a0, b0, zf, 0, 0, 0);
        acc = __builtin_amdgcn_mfma_f32_16x16x32_f16(a1, b1, acc, 0, 0, 0);
        const float bias = Bm[lcol];

        if (m == 0) {
#pragma unroll
            for (int r = 0; r < 4; ++r)
                Qg[((size_t)b * NS + n0 + quad * 4 + r) * ND + lcol] =
                    (_Float16)((acc[r] + bias) * LOG2E);
        } else if (m == 1) {
#pragma unroll
            for (int r = 0; r < 4; ++r)
                Kg[((size_t)b * NS + n0 + quad * 4 + r) * ND + lcol] = (_Float16)(acc[r] + bias);
        } else {
#pragma unroll
            for (int r = 0; r < 4; ++r)
                vt[lcol * 18 + quad * 4 + r] = (_Float16)(acc[r] + bias);
        }
    }
    __syncthreads();
    {
        const int d = tid >> 2, seg = tid & 3;
        uint2 p = *(uint2*)&vt[d * 18 + seg * 4];
        *(uint2*)(Vt + ((size_t)b * ND + d) * NS + n0 + seg * 4) = p;
    }
}

// ---------------- fused masked attention: bf16-packed e-cache, small footprint -
// grid: 1024 blocks (b = blk&7 -> XCD-pinned batch), 512 thr = 8 waves.
// Wave wv's chunk t = keys [(t*8+wv)*64, +64) — interleaved for L2 locality.
// Pass 1: e = 2^(s') packed bf16 2-per-reg (32 regs), l = sum e (fp32).
// Mask: e > l/N <=> p > mean(p) = 1/N. Pass 2: unpack -> LDS transpose -> PV.
// Register diet: ring-2 K prefetch, 32-key PV chunks, fp16 partial-O in LDS.
__global__ __launch_bounds__(512, 4) void attn(
    const _Float16* __restrict__ Qg,
    const _Float16* __restrict__ Kg,
    const _Float16* __restrict__ Vt,
    float* __restrict__ out)
{
    // pbuf: 8 waves x 16 rows x 40 stride fp16 = 10240 B
    // obuf (union): 128 rows x 72 stride fp16 = 18432 B
    __shared__ __align__(16) unsigned char smraw[128 * 72 * 2];
    __shared__ float lsh[128];
    _Float16* pbuf = (_Float16*)smraw;
    _Float16* obuf = (_Float16*)smraw;

    const int tid  = threadIdx.x;
    const int wv   = tid >> 6;
    const int l    = tid & 63;
    const int quad = l >> 4;
    const int tx   = l & 15;

    const int b  = blockIdx.x & 7;
    const int q0 = (blockIdx.x >> 3) * 16;

    const _Float16* Qb = Qg + ((size_t)b * NS + q0) * ND;
    const _Float16* Kb = Kg + (size_t)b * NS * ND;
    const _Float16* Vb = Vt + (size_t)b * ND * NS;

    half8 qf0 = *(const half8*)(Qb + (size_t)tx * ND + quad * 8);
    half8 qf1 = *(const half8*)(Qb + (size_t)tx * ND + 32 + quad * 8);

    const floatx4 zf = {0.f, 0.f, 0.f, 0.f};

    // tile s (0..15): key row = ((s>>2)*8 + wv)*64 + (s&3)*16 + tx
#define KROW(s) ((((s) >> 2) * 8 + wv) * 64 + ((s) & 3) * 16 + tx)

    // ---- pass 1: e = 2^s packed bf16; ring-2 K prefetch ----
    unsigned e2[32];
    float lacc[4] = {0.f, 0.f, 0.f, 0.f};
    {
        half8 kf[2][2];
#pragma unroll
        for (int s = 0; s < 2; ++s) {
            const _Float16* Kr = Kb + (size_t)KROW(s) * ND + quad * 8;
            kf[s][0] = *(const half8*)Kr;
            kf[s][1] = *(const half8*)(Kr + 32);
        }
#pragma unroll
        for (int s = 0; s < 16; ++s) {
            floatx4 c = __builtin_amdgcn_mfma_f32_16x16x32_f16(qf0, kf[s & 1][0], zf, 0, 0, 0);
            c = __builtin_amdgcn_mfma_f32_16x16x32_f16(qf1, kf[s & 1][1], c, 0, 0, 0);
            if (s + 2 < 16) {
                const _Float16* Kr = Kb + (size_t)KROW(s + 2) * ND + quad * 8;
                kf[s & 1][0] = *(const half8*)Kr;
                kf[s & 1][1] = *(const half8*)(Kr + 32);
            }
            float e0 = __builtin_amdgcn_exp2f(c[0]);
            float e1 = __builtin_amdgcn_exp2f(c[1]);
            float eA = __builtin_amdgcn_exp2f(c[2]);
            float e3 = __builtin_amdgcn_exp2f(c[3]);
            lacc[0] += e0; lacc[1] += e1; lacc[2] += eA; lacc[3] += e3;
            e2[2 * s]     = f2bf(e0) | (f2bf(e1) << 16);
            e2[2 * s + 1] = f2bf(eA) | (f2bf(e3) << 16);
        }
    }
#pragma unroll
    for (int off = 1; off < 16; off <<= 1)
#pragma unroll
        for (int r = 0; r < 4; ++r)
            lacc[r] += __shfl_xor(lacc[r], off);
    if (tx == 0) {
#pragma unroll
        for (int r = 0; r < 4; ++r)
            lsh[wv * 16 + quad * 4 + r] = lacc[r];
    }
    __syncthreads();

    float inv[4], thr[4];
#pragma unroll
    for (int r = 0; r < 4; ++r) {
        const int row = quad * 4 + r;
        float L = 0.f;
#pragma unroll
        for (int w = 0; w < 8; ++w) L += lsh[w * 16 + row];
        inv[r] = 1.f / L;
        thr[r] = L * (1.f / (float)NS);
    }

    // ---- pass 2: 8 chunks of 32 keys: unpack e, mask, LDS transpose, PV ----
    floatx4 o[4] = {zf, zf, zf, zf};
    _Float16* pb = pbuf + wv * (16 * 40);

#pragma unroll
    for (int c = 0; c < 8; ++c) {
        // chunk c = keys ((c>>1)*8 + wv)*64 + (c&1)*32 .. +31  (matches s = 2c, 2c+1)
        const int vkb = ((c >> 1) * 8 + wv) * 64 + (c & 1) * 32;
        half8 vf[4];
#pragma unroll
        for (int nt = 0; nt < 4; ++nt)   // V early: consumed after LDS round-trip
            vf[nt] = *(const half8*)(Vb + (size_t)(nt * 16 + tx) * NS + vkb + quad * 8);

#pragma unroll
        for (int h = 0; h < 2; ++h) {
            const int s = 2 * c + h;
            unsigned u0 = e2[2 * s], u1 = e2[2 * s + 1];
            float ev[4] = {bf2f(u0 & 0xffffu), bf2f(u0 >> 16),
                           bf2f(u1 & 0xffffu), bf2f(u1 >> 16)};
#pragma unroll
            for (int r = 0; r < 4; ++r) {
                float w = (ev[r] > thr[r]) ? ev[r] * inv[r] : 0.f;
                pb[(quad * 4 + r) * 40 + h * 16 + tx] = (_Float16)w;
            }
        }
        // per-wave DS FIFO: this read sees this wave's writes above
        half8 af = *(const half8*)(pb + tx * 40 + quad * 8);
#pragma unroll
        for (int nt = 0; nt < 4; ++nt)
            o[nt] = __builtin_amdgcn_mfma_f32_16x16x32_f16(af, vf[nt], o[nt], 0, 0, 0);
    }

    __syncthreads();   // all pbuf reads complete before obuf reuse
#pragma unroll
    for (int nt = 0; nt < 4; ++nt)
#pragma unroll
        for (int r = 0; r < 4; ++r)
            obuf[(wv * 16 + quad * 4 + r) * 72 + nt * 16 + tx] = (_Float16)o[nt][r];
    __syncthreads();

    {
        const int row = tid >> 5;             // 0..15
        const int c2  = (tid & 31) * 2;       // 32 col-pairs
        float sx = 0.f, sy = 0.f;
#pragma unroll
        for (int w = 0; w < 8; ++w) {
            half2v v = *(half2v*)&obuf[(w * 16 + row) * 72 + c2];
            sx += (float)v.x; sy += (float)v.y;
        }
        float2 res = {sx, sy};
        *(float2*)(out + ((size_t)b * NS + q0 + row) * ND + c2) = res;
    }
#undef KROW
}

extern "C" void kernel_launch(void* const* d_in, const int* in_sizes, int n_in,
                              void* d_out, int out_size, void* d_ws, size_t ws_size,
                              hipStream_t stream) {
    const float* x  = (const float*)d_in[0];
    const float* Wq = (const float*)d_in[1];
    const float* bq = (const float*)d_in[2];
    const float* Wk = (const float*)d_in[3];
    const float* bk = (const float*)d_in[4];
    const float* Wv = (const float*)d_in[5];
    const float* bv = (const float*)d_in[6];

    _Float16* Qg = (_Float16*)d_ws;
    _Float16* Kg = Qg + (size_t)NB * NS * ND;
    _Float16* Vt = Kg + (size_t)NB * NS * ND;

    qkv_proj<<<NB * (NS / 16), 256, 0, stream>>>(x, Wq, bq, Wk, bk, Wv, bv, Qg, Kg, Vt);
    attn<<<NB * (NS / 16), 512, 0, stream>>>(Qg, Kg, Vt, (float*)d_out);
}